// Round 10
// baseline (808.711 us; speedup 1.0000x reference)
//
#include <hip/hip_runtime.h>
#include <hip/hip_bf16.h>
#include <stdint.h>

#define N_TOK 4096
#define DIM   512
#define GAMMA_C 0.5f
#define EPS_C   1e-5f

using bf16 = __hip_bfloat16;
typedef __bf16 bf16x8_t __attribute__((ext_vector_type(8)));
typedef float  f32x4_t  __attribute__((ext_vector_type(4)));
typedef __attribute__((ext_vector_type(8))) unsigned short u16x8;

typedef __attribute__((address_space(1))) void gvoid_t;
typedef __attribute__((address_space(3))) void lvoid_t;

__device__ __forceinline__ float bf2f(unsigned short u){
  union { unsigned int i; float f; } c; c.i = ((unsigned int)u) << 16; return c.f;
}
__device__ __forceinline__ unsigned short f2b_rne(float f){
  union { float f; unsigned int u; } c; c.f = f;
  unsigned int r = c.u + 0x7FFFu + ((c.u >> 16) & 1u);
  return (unsigned short)(r >> 16);
}
__device__ __forceinline__ void store_out(float* p, float v){ *p = v; }
__device__ __forceinline__ void store_out(bf16* p, float v){
  *reinterpret_cast<unsigned short*>(p) = f2b_rne(v);
}

// ============ format detection ============
// flags[0]: 1 => numeric inputs are bf16, 0 => f32   (R5 run: f32 confirmed)
// flags[1]: mask kind: 0=int32 words, 1=uint8 bytes, 2=f32 words, 3=16-bit halves
__global__ void classify(const uint32_t* __restrict__ xw,
                         const uint32_t* __restrict__ mw,
                         int* __restrict__ flags){
  __shared__ int cexp, i32b, u8b, f32b;
  int tid = threadIdx.x;
  if (tid == 0){ cexp = 0; i32b = 0; u8b = 0; f32b = 0; }
  __syncthreads();
  int c = 0;
  for (int i = tid; i < 1024; i += 256){
    uint32_t w = xw[i];
    uint32_t e = (w >> 7) & 0xFFu;
    if (e > 133u) c++;
  }
  if (c) atomicAdd(&cexp, c);
  int a = 0, b = 0, d = 0;
  for (int i = tid; i < 4096; i += 256){
    uint32_t w = mw[i];
    if (w > 1u) a = 1;
    if (w & 0xFEFEFEFEu) b = 1;
    if (w != 0u && w != 0x3F800000u) d = 1;
  }
  if (a) atomicOr(&i32b, 1);
  if (b) atomicOr(&u8b, 1);
  if (d) atomicOr(&f32b, 1);
  __syncthreads();
  if (tid == 0){
    flags[0] = (cexp >= 64) ? 0 : 1;
    flags[1] = !i32b ? 0 : (!u8b ? 1 : (!f32b ? 2 : 3));
  }
}

__global__ __launch_bounds__(256) void pack_mask(const void* __restrict__ m,
                                                 uint32_t* __restrict__ bits,
                                                 const int* __restrict__ flags){
  int w = blockIdx.x * 256 + threadIdx.x;    // N*N/32 words
  int kind = flags[1];
  uint32_t o = 0;
  if (kind == 0 || kind == 2){
    const uint32_t* p = (const uint32_t*)m + (size_t)w * 32;
    #pragma unroll
    for (int j = 0; j < 32; ++j) o |= (p[j] != 0u ? 1u : 0u) << j;
  } else if (kind == 1){
    const uint8_t* p = (const uint8_t*)m + (size_t)w * 32;
    #pragma unroll
    for (int j = 0; j < 32; ++j) o |= (p[j] != 0 ? 1u : 0u) << j;
  } else {
    const uint16_t* p = (const uint16_t*)m + (size_t)w * 32;
    #pragma unroll
    for (int j = 0; j < 32; ++j) o |= (p[j] != 0 ? 1u : 0u) << j;
  }
  bits[w] = o;
}

// ============ input prep (format-adaptive) ============
__global__ __launch_bounds__(256) void prep_x(const void* __restrict__ s,
                                              unsigned short* __restrict__ xb,
                                              float* __restrict__ xf,
                                              const int* __restrict__ flags){
  int i = blockIdx.x * 256 + threadIdx.x;    // N*DIM
  if (*flags){
    unsigned short u = ((const unsigned short*)s)[i];
    xb[i] = u; xf[i] = bf2f(u);
  } else {
    float f = ((const float*)s)[i];
    xb[i] = f2b_rne(f); xf[i] = f;
  }
}

__global__ __launch_bounds__(256) void cvt_vec(const void* __restrict__ s,
                                               float* __restrict__ d, int n,
                                               const int* __restrict__ flags){
  int i = blockIdx.x * 256 + threadIdx.x;
  if (i >= n) return;
  d[i] = *flags ? bf2f(((const unsigned short*)s)[i]) : ((const float*)s)[i];
}

// weight [R][C] (f32 or bf16 per flag) -> wT bf16 [C][R]
__global__ __launch_bounds__(256) void trw(const void* __restrict__ s,
                                           unsigned short* __restrict__ d,
                                           int R, int C, const int* __restrict__ flags){
  __shared__ unsigned short t[32][33];
  int bx = blockIdx.x * 32, by = blockIdx.y * 32;
  int tx = threadIdx.x & 31, ty = threadIdx.x >> 5;
  bool b16 = (*flags != 0);
  #pragma unroll
  for (int i = 0; i < 32; i += 8){
    size_t idx = (size_t)(by + ty + i) * C + bx + tx;
    t[ty + i][tx] = b16 ? ((const unsigned short*)s)[idx]
                        : f2b_rne(((const float*)s)[idx]);
  }
  __syncthreads();
  #pragma unroll
  for (int i = 0; i < 32; i += 8)
    d[(size_t)(bx + ty + i) * R + by + tx] = t[tx][ty + i];
}

// bf16 [R,C] (row stride ld) -> bf16 [C,R]
__global__ __launch_bounds__(256) void tbf16(const bf16* __restrict__ s, int ld,
                                             bf16* __restrict__ d, int R, int C){
  __shared__ unsigned short t[32][33];
  int bx = blockIdx.x * 32, by = blockIdx.y * 32;
  int tx = threadIdx.x & 31, ty = threadIdx.x >> 5;
  #pragma unroll
  for (int i = 0; i < 32; i += 8)
    t[ty + i][tx] = reinterpret_cast<const unsigned short*>(s)[(size_t)(by + ty + i) * ld + bx + tx];
  __syncthreads();
  #pragma unroll
  for (int i = 0; i < 32; i += 8)
    reinterpret_cast<unsigned short*>(d)[(size_t)(bx + ty + i) * R + by + tx] = t[tx][ty + i];
}

// ============ GEMM: C[M,N] = A[M,K] @ B[N,K]^T ============
// 128x128 tile, BK=32, 4 waves (2x2 of 64x64), global_load_lds width-16 staging
// (m97 pattern; proven equivalent to reg-staging by R1==R3 bit-identical outputs).
__device__ __forceinline__ void stage_tile(const bf16* __restrict__ g, int ld,
                                           bf16* lds, int tid){
  int wid = tid >> 6;
  const bf16* s0 = g + (size_t)(tid >> 2) * ld + (tid & 3) * 8;
  __builtin_amdgcn_global_load_lds((gvoid_t*)(void*)s0,
      (lvoid_t*)(void*)((char*)lds + wid * 1024), 16, 0, 0);
  const bf16* s1 = g + (size_t)(64 + (tid >> 2)) * ld + (tid & 3) * 8;
  __builtin_amdgcn_global_load_lds((gvoid_t*)(void*)s1,
      (lvoid_t*)(void*)((char*)lds + 4096 + wid * 1024), 16, 0, 0);
}

// EP: 0=store  1=bias+gelu(exact)  2=bias+relu  3=divide-by-rowsum  4=bias
template<typename OutT, int EP>
__global__ __launch_bounds__(256) void gemm_bt(
    const bf16* __restrict__ A, int lda,
    const bf16* __restrict__ B, int ldb,
    OutT* __restrict__ C, int ldc, int K,
    const float* __restrict__ bias, const float* __restrict__ rowsum)
{
  __shared__ __align__(16) bf16 Al[128 * 32];
  __shared__ __align__(16) bf16 Bl[128 * 32];
  const int tid = threadIdx.x, lane = tid & 63;
  const int wm = tid >> 7, wn = (tid >> 6) & 1;
  const int tm = blockIdx.y * 128, tn = blockIdx.x * 128;
  f32x4_t acc[4][4] = {};
  const bf16* Ag = A + (size_t)tm * lda;
  const bf16* Bg = B + (size_t)tn * ldb;
  const int co = (lane >> 4) * 8;      // k-offset of this lane's 8 contiguous elems
  const int rA = lane & 15;            // row within 16-row MFMA block
  for (int k0 = 0; k0 < K; k0 += 32){
    stage_tile(Ag + k0, lda, Al, tid);
    stage_tile(Bg + k0, ldb, Bl, tid);
    __syncthreads();
    bf16x8_t af[4], bq[4];
    #pragma unroll
    for (int mi = 0; mi < 4; ++mi)
      af[mi] = *(const bf16x8_t*)&Al[(wm * 64 + mi * 16 + rA) * 32 + co];
    #pragma unroll
    for (int ni = 0; ni < 4; ++ni)
      bq[ni] = *(const bf16x8_t*)&Bl[(wn * 64 + ni * 16 + rA) * 32 + co];
    #pragma unroll
    for (int mi = 0; mi < 4; ++mi)
      #pragma unroll
      for (int ni = 0; ni < 4; ++ni)
        acc[mi][ni] = __builtin_amdgcn_mfma_f32_16x16x32_bf16(af[mi], bq[ni], acc[mi][ni], 0, 0, 0);
    __syncthreads();
  }
  // C/D map validated on-HW (R5 probe): value(lane,reg) = D[(lane>>4)*4+reg][lane&15]
  const int r0 = (lane >> 4) * 4, c0 = lane & 15;
  #pragma unroll
  for (int mi = 0; mi < 4; ++mi){
    #pragma unroll
    for (int ni = 0; ni < 4; ++ni){
      int col = tn + wn * 64 + ni * 16 + c0;
      float bv = 0.f;
      if constexpr (EP == 1 || EP == 2 || EP == 4) bv = bias[col];
      #pragma unroll
      for (int r = 0; r < 4; ++r){
        int row = tm + wm * 64 + mi * 16 + r0 + r;
        float v = acc[mi][ni][r];
        if constexpr (EP == 1){ v += bv; v = 0.5f * v * (1.f + erff(v * 0.70710678118f)); }
        else if constexpr (EP == 2){ v += bv; v = fmaxf(v, 0.f); }
        else if constexpr (EP == 3){ v /= rowsum[row]; }
        else if constexpr (EP == 4){ v += bv; }
        store_out(&C[(size_t)row * ldc + col], v);
      }
    }
  }
}

// ============ dual-softmax combine (in-place over Sr) ============
__global__ __launch_bounds__(256) void combine(bf16* __restrict__ Sr, const bf16* __restrict__ Sf,
    const uint32_t* __restrict__ br, const uint32_t* __restrict__ bfm,
    float* __restrict__ rowsum, float scale){
  const int C = N_TOK;
  int row = blockIdx.x, tid = threadIdx.x;
  size_t base = (size_t)row * C + tid * 16;
  const u16x8* pr = (const u16x8*)(Sr + base);
  const u16x8* pf = (const u16x8*)(Sf + base);
  u16x8 r0 = pr[0], r1 = pr[1], f0 = pf[0], f1 = pf[1];
  unsigned mr = br[row * (C / 32) + (tid >> 1)] >> ((tid & 1) * 16);
  unsigned mf = bfm[row * (C / 32) + (tid >> 1)] >> ((tid & 1) * 16);
  float vr[16], vf[16];
  float lmax = -3e38f;
  #pragma unroll
  for (int j = 0; j < 16; ++j){
    unsigned short u = (j < 8) ? r0[j] : r1[j - 8];
    float v = bf2f(u) * scale;
    if ((mr >> j) & 1) v = -1e9f;
    vr[j] = v; lmax = fmaxf(lmax, v);
    u = (j < 8) ? f0[j] : f1[j - 8];
    v = bf2f(u) * scale;
    if ((mf >> j) & 1) v = -1e9f;
    vf[j] = v; lmax = fmaxf(lmax, v);
  }
  #pragma unroll
  for (int o = 32; o; o >>= 1) lmax = fmaxf(lmax, __shfl_xor(lmax, o));
  __shared__ float sred[4];
  __shared__ float smax;
  if ((tid & 63) == 0) sred[tid >> 6] = lmax;
  __syncthreads();
  if (tid == 0) smax = fmaxf(fmaxf(sred[0], sred[1]), fmaxf(sred[2], sred[3]));
  __syncthreads();
  float m = smax;
  float lsum = 0.f;
  u16x8 o0, o1;
  #pragma unroll
  for (int j = 0; j < 16; ++j){
    float p = __expf(vr[j] - m) + GAMMA_C * __expf(vf[j] - m);
    lsum += p;
    unsigned short ub = f2b_rne(p);
    if (j < 8) o0[j] = ub; else o1[j - 8] = ub;
  }
  ((u16x8*)(Sr + base))[0] = o0;
  ((u16x8*)(Sr + base))[1] = o1;
  #pragma unroll
  for (int o = 32; o; o >>= 1) lsum += __shfl_xor(lsum, o);
  __syncthreads();
  if ((tid & 63) == 0) sred[tid >> 6] = lsum;
  __syncthreads();
  if (tid == 0) rowsum[row] = sred[0] + sred[1] + sred[2] + sred[3];
}

// ============ residual add + LayerNorm ============
__global__ __launch_bounds__(256) void add_ln(const float* __restrict__ v, const float* __restrict__ res,
    const float* __restrict__ g, const float* __restrict__ b,
    float* __restrict__ of, bf16* __restrict__ ob){
  const int C = DIM;
  int row = blockIdx.x, tid = threadIdx.x;
  size_t base = (size_t)row * C;
  float x0 = v[base + tid] + res[base + tid];
  float x1 = v[base + tid + 256] + res[base + tid + 256];
  float s = x0 + x1, q = x0 * x0 + x1 * x1;
  #pragma unroll
  for (int o = 32; o; o >>= 1){ s += __shfl_xor(s, o); q += __shfl_xor(q, o); }
  __shared__ float s4[4], q4[4];
  __shared__ float smu, srs;
  if ((tid & 63) == 0){ s4[tid >> 6] = s; q4[tid >> 6] = q; }
  __syncthreads();
  if (tid == 0){
    float S = s4[0] + s4[1] + s4[2] + s4[3];
    float Q = q4[0] + q4[1] + q4[2] + q4[3];
    float mu = S / C; float var = Q / C - mu * mu;
    smu = mu; srs = rsqrtf(var + EPS_C);
  }
  __syncthreads();
  float mu = smu, rs = srs;
  float y0 = (x0 - mu) * rs * g[tid] + b[tid];
  float y1 = (x1 - mu) * rs * g[tid + 256] + b[tid + 256];
  of[base + tid] = y0; of[base + tid + 256] = y1;
  store_out(&ob[base + tid], y0); store_out(&ob[base + tid + 256], y1);
}

// ============ head2: out[4096,64] = h1[4096,256] @ w2[256,64] + b2 ============
__global__ __launch_bounds__(256) void head2k(const bf16* __restrict__ h, const float* __restrict__ w,
                                              const float* __restrict__ b, void* __restrict__ out,
                                              const int* __restrict__ flags){
  int row = blockIdx.x, tid = threadIdx.x;
  __shared__ float hr[256];
  __shared__ float part[4][64];
  hr[tid] = bf2f(reinterpret_cast<const unsigned short*>(h)[(size_t)row * 256 + tid]);
  __syncthreads();
  int j = tid & 63, kq = tid >> 6;
  float s = 0.f;
  #pragma unroll 8
  for (int k = kq * 64; k < kq * 64 + 64; ++k) s += hr[k] * w[k * 64 + j];
  part[kq][j] = s;
  __syncthreads();
  if (tid < 64){
    float v = part[0][tid] + part[1][tid] + part[2][tid] + part[3][tid] + b[tid];
    size_t idx = (size_t)row * 64 + tid;
    if (*flags) ((unsigned short*)out)[idx] = f2b_rne(v);
    else        ((float*)out)[idx] = v;
  }
}

// ============ launch ============
extern "C" void kernel_launch(void* const* d_in, const int* in_sizes, int n_in,
                              void* d_out, int out_size, void* d_ws, size_t ws_size,
                              hipStream_t stream){
  const void* x   = d_in[0];
  const void* mr  = d_in[1];
  const void* mfk = d_in[2];
  const void* Wenc[5] = {d_in[3], d_in[4], d_in[5], d_in[6], d_in[7]};
  const void* Wdec[5] = {d_in[8], d_in[9], d_in[10], d_in[11], d_in[12]};
  const void* ffw1 = d_in[13]; const void* ffb1 = d_in[14];
  const void* ffw2 = d_in[15]; const void* ffb2 = d_in[16];
  const void* ln1g = d_in[17]; const void* ln1b = d_in[18];
  const void* ln2g = d_in[19]; const void* ln2b = d_in[20];
  const void* ln3g = d_in[21]; const void* ln3b = d_in[22];
  const void* hw1  = d_in[23]; const void* hb1  = d_in[24];
  const void* hw2  = d_in[25]; const void* hb2  = d_in[26];

  char* ws = (char*)d_ws;
  size_t o = 0;
  auto alloc = [&](size_t bytes) -> char* {
    char* p = ws + o; o += (bytes + 255) & ~(size_t)255; return p;
  };
  const int N = N_TOK;
  int*      flags = (int*)alloc(16);
  uint32_t* bitsr = (uint32_t*)alloc((size_t)N * N / 8);
  uint32_t* bitsf = (uint32_t*)alloc((size_t)N * N / 8);
  bf16* wTenc = (bf16*)alloc((size_t)2560 * 512 * 2);
  bf16* wTdec = (bf16*)alloc((size_t)2560 * 512 * 2);
  bf16* ff1T  = (bf16*)alloc((size_t)2048 * 512 * 2);
  bf16* ff2T  = (bf16*)alloc((size_t)512 * 2048 * 2);
  bf16* h1T   = (bf16*)alloc((size_t)256 * 512 * 2);
  float* ffb1f = (float*)alloc(2048 * 4);
  float* ffb2f = (float*)alloc(512 * 4);
  float* ln1gf = (float*)alloc(512 * 4); float* ln1bf = (float*)alloc(512 * 4);
  float* ln2gf = (float*)alloc(512 * 4); float* ln2bf = (float*)alloc(512 * 4);
  float* ln3gf = (float*)alloc(512 * 4); float* ln3bf = (float*)alloc(512 * 4);
  float* hb1f  = (float*)alloc(256 * 4);
  float* w2f   = (float*)alloc(256 * 64 * 4);
  float* hb2f  = (float*)alloc(64 * 4);
  bf16* xb    = (bf16*)alloc((size_t)N * 512 * 2);
  float* xf   = (float*)alloc((size_t)N * 512 * 4);
  bf16* QKV   = (bf16*)alloc((size_t)N * 2560 * 2);
  bf16* Vt    = (bf16*)alloc((size_t)512 * N * 2);
  bf16* Sr    = (bf16*)alloc((size_t)N * N * 2);
  bf16* Sf    = (bf16*)alloc((size_t)N * N * 2);
  float* rowsum = (float*)alloc((size_t)N * 4);
  float* attn   = (float*)alloc((size_t)N * 512 * 4);
  float* hidAf  = (float*)alloc((size_t)N * 512 * 4);
  bf16*  hidAb  = (bf16*)alloc((size_t)N * 512 * 2);
  bf16*  ffg    = (bf16*)alloc((size_t)N * 2048 * 2);
  float* ff2o   = (float*)alloc((size_t)N * 512 * 4);
  float* hidBf  = (float*)alloc((size_t)N * 512 * 4);
  bf16*  hidBb  = (bf16*)alloc((size_t)N * 512 * 2);
  bf16*  recb   = (bf16*)alloc((size_t)N * 512 * 2);
  bf16*  h1buf  = (bf16*)alloc((size_t)N * 256 * 2);

  const float scale = 0.04419417382415922f;  // 1/sqrt(512)

  // probes + masks
  classify<<<1, 256, 0, stream>>>((const uint32_t*)x, (const uint32_t*)mr, flags);
  pack_mask<<<(N * N / 32) / 256, 256, 0, stream>>>(mr, bitsr, flags);
  pack_mask<<<(N * N / 32) / 256, 256, 0, stream>>>(mfk, bitsf, flags);

  // input prep
  prep_x<<<(N * 512) / 256, 256, 0, stream>>>(x, (unsigned short*)xb, xf, flags);
  for (int i = 0; i < 5; ++i){
    trw<<<dim3(16, 16), 256, 0, stream>>>(Wenc[i], (unsigned short*)(wTenc + (size_t)i * 512 * 512), 512, 512, flags);
    trw<<<dim3(16, 16), 256, 0, stream>>>(Wdec[i], (unsigned short*)(wTdec + (size_t)i * 512 * 512), 512, 512, flags);
  }
  trw<<<dim3(64, 16), 256, 0, stream>>>(ffw1, (unsigned short*)ff1T, 512, 2048, flags);
  trw<<<dim3(16, 64), 256, 0, stream>>>(ffw2, (unsigned short*)ff2T, 2048, 512, flags);
  trw<<<dim3(8, 16), 256, 0, stream>>>(hw1, (unsigned short*)h1T, 512, 256, flags);
  cvt_vec<<<8, 256, 0, stream>>>(ffb1, ffb1f, 2048, flags);
  cvt_vec<<<2, 256, 0, stream>>>(ffb2, ffb2f, 512, flags);
  cvt_vec<<<2, 256, 0, stream>>>(ln1g, ln1gf, 512, flags);
  cvt_vec<<<2, 256, 0, stream>>>(ln1b, ln1bf, 512, flags);
  cvt_vec<<<2, 256, 0, stream>>>(ln2g, ln2gf, 512, flags);
  cvt_vec<<<2, 256, 0, stream>>>(ln2b, ln2bf, 512, flags);
  cvt_vec<<<2, 256, 0, stream>>>(ln3g, ln3gf, 512, flags);
  cvt_vec<<<2, 256, 0, stream>>>(ln3b, ln3bf, 512, flags);
  cvt_vec<<<1, 256, 0, stream>>>(hb1, hb1f, 256, flags);
  cvt_vec<<<64, 256, 0, stream>>>(hw2, w2f, 256 * 64, flags);
  cvt_vec<<<1, 256, 0, stream>>>(hb2, hb2f, 64, flags);

  // ---- encoder block ----
  gemm_bt<bf16, 0><<<dim3(20, 32), 256, 0, stream>>>(xb, 512, wTenc, 512, QKV, 2560, 512, nullptr, nullptr);
  tbf16<<<dim3(16, 128), 256, 0, stream>>>(QKV + 2048, 2560, Vt, N, 512);
  gemm_bt<bf16, 0><<<dim3(32, 32), 256, 0, stream>>>(QKV + 0, 2560, QKV + 512, 2560, Sr, N, 512, nullptr, nullptr);
  gemm_bt<bf16, 0><<<dim3(32, 32), 256, 0, stream>>>(QKV + 1024, 2560, QKV + 1536, 2560, Sf, N, 512, nullptr, nullptr);
  combine<<<N, 256, 0, stream>>>(Sr, Sf, bitsr, bitsf, rowsum, scale);
  gemm_bt<float, 3><<<dim3(4, 32), 256, 0, stream>>>(Sr, N, Vt, N, attn, 512, N, nullptr, rowsum);
  add_ln<<<N, 256, 0, stream>>>(attn, xf, ln1gf, ln1bf, hidAf, hidAb);
  gemm_bt<bf16, 1><<<dim3(16, 32), 256, 0, stream>>>(hidAb, 512, ff1T, 512, ffg, 2048, 512, ffb1f, nullptr);
  gemm_bt<float, 4><<<dim3(4, 32), 256, 0, stream>>>(ffg, 2048, ff2T, 2048, ff2o, 512, 2048, ffb2f, nullptr);
  add_ln<<<N, 256, 0, stream>>>(ff2o, hidAf, ln2gf, ln2bf, hidBf, hidBb);

  // ---- decoder block ----
  gemm_bt<bf16, 0><<<dim3(20, 32), 256, 0, stream>>>(hidBb, 512, wTdec, 512, QKV, 2560, 512, nullptr, nullptr);
  tbf16<<<dim3(16, 128), 256, 0, stream>>>(QKV + 2048, 2560, Vt, N, 512);
  gemm_bt<bf16, 0><<<dim3(32, 32), 256, 0, stream>>>(QKV + 0, 2560, QKV + 512, 2560, Sr, N, 512, nullptr, nullptr);
  gemm_bt<bf16, 0><<<dim3(32, 32), 256, 0, stream>>>(QKV + 1024, 2560, QKV + 1536, 2560, Sf, N, 512, nullptr, nullptr);
  combine<<<N, 256, 0, stream>>>(Sr, Sf, bitsr, bitsf, rowsum, scale);
  gemm_bt<float, 3><<<dim3(4, 32), 256, 0, stream>>>(Sr, N, Vt, N, attn, 512, N, nullptr, rowsum);
  add_ln<<<N, 256, 0, stream>>>(attn, hidBf, ln3gf, ln3bf, hidAf, recb);

  // ---- head ----
  // BUGFIX (R1-R5): h1T is [256][512] row-major => ldb must be 512 (was 256).
  gemm_bt<bf16, 2><<<dim3(2, 32), 256, 0, stream>>>(recb, 512, h1T, 512, h1buf, 256, 512, hb1f, nullptr);
  head2k<<<N, 256, 0, stream>>>(h1buf, w2f, hb2f, d_out, flags);
  (void)in_sizes; (void)n_in; (void)out_size; (void)ws_size;
}